// Round 1
// baseline (351.256 us; speedup 1.0000x reference)
//
#include <hip/hip_runtime.h>
#include <math.h>

#define S_LEN 262144
#define N 128
#define BR 64
#define TPB 256

__device__ __forceinline__ float wave_reduce(float v) {
    #pragma unroll
    for (int off = 32; off > 0; off >>= 1)
        v += __shfl_down(v, off, 64);
    return v;
}

// Computes M = W_K^T @ W_Q (128x128) into ws, and l1 = sum(|sigmoid(M)|) into out[1].
__global__ void mk_kernel(const float* __restrict__ WQ, const float* __restrict__ WK,
                          float* __restrict__ M, float* __restrict__ out) {
    const int i = blockIdx.x;   // row of M
    const int j = threadIdx.x;  // col of M
    float acc = 0.f;
    #pragma unroll 8
    for (int r = 0; r < N; ++r)
        acc = fmaf(WK[r * N + i], WQ[r * N + j], acc);
    M[i * N + j] = acc;

    float sg = fabsf(1.0f / (1.0f + __expf(-acc)));
    float ws = wave_reduce(sg);
    __shared__ float red[2];
    const int lane = j & 63, w = j >> 6;
    if (lane == 0) red[w] = ws;
    __syncthreads();
    if (j == 0) atomicAdd(&out[1], red[0] + red[1]);
}

// Fused: z = Input @ M ; Out = softplus(z) * rowsum(Input) ;
// loss += sum((Out[s] - Input[s+1])^2) for s < S-1, scaled by 1/((S-1)*N).
__global__ __launch_bounds__(TPB, 2) void main_kernel(
    const float* __restrict__ In, const float* __restrict__ M,
    float* __restrict__ out, float inv_denom) {
    __shared__ float sIn[BR][68];     // 64 rows x 64 k (half-K), padded to 68
    __shared__ float sM[64][N];       // 64 k (half-K) x 128 cols
    __shared__ float sRow[BR];        // per-row sums over full K
    __shared__ float sRed[TPB / 64];

    const int tid = threadIdx.x;
    const int tx = tid & 15;          // col group: cols tx*8 .. tx*8+7
    const int ty = tid >> 4;          // row group: rows ty*4 .. ty*4+3
    const long r0 = (long)blockIdx.x * BR;

    float acc[4][8];
    #pragma unroll
    for (int i = 0; i < 4; ++i)
        #pragma unroll
        for (int j = 0; j < 8; ++j)
            acc[i][j] = 0.f;

    if (tid < BR) sRow[tid] = 0.f;

    for (int kb = 0; kb < 2; ++kb) {
        __syncthreads();  // covers sRow init and prior-iter tile readers
        // stage Input half-tile: 64x64 floats = 1024 float4
        #pragma unroll
        for (int w = 0; w < 4; ++w) {
            const int q = tid + w * TPB;        // 0..1023
            const int r = q >> 4;
            const int kq = (q & 15) << 2;
            const float4 v = *(const float4*)&In[(r0 + r) * N + kb * 64 + kq];
            *(float4*)&sIn[r][kq] = v;
        }
        // stage M half-tile: 64x128 floats = 2048 float4
        #pragma unroll
        for (int w = 0; w < 8; ++w) {
            const int q = tid + w * TPB;        // 0..2047
            const int kk = q >> 5;
            const int c = (q & 31) << 2;
            const float4 v = *(const float4*)&M[(kb * 64 + kk) * N + c];
            *(float4*)&sM[kk][c] = v;
        }
        __syncthreads();

        // row sums (one wave, overlapped with FMA loop of other waves)
        if (tid < BR) {
            float s = 0.f;
            #pragma unroll 16
            for (int kk = 0; kk < 64; ++kk) s += sIn[tid][kk];
            sRow[tid] += s;
        }

        for (int kk = 0; kk < 64; kk += 4) {
            float a[4][4];   // [row][k]
            float b[4][8];   // [k][col]
            #pragma unroll
            for (int i = 0; i < 4; ++i)
                *(float4*)&a[i][0] = *(const float4*)&sIn[ty * 4 + i][kk];
            #pragma unroll
            for (int k = 0; k < 4; ++k) {
                *(float4*)&b[k][0] = *(const float4*)&sM[kk + k][tx * 8];
                *(float4*)&b[k][4] = *(const float4*)&sM[kk + k][tx * 8 + 4];
            }
            #pragma unroll
            for (int i = 0; i < 4; ++i)
                #pragma unroll
                for (int k = 0; k < 4; ++k)
                    #pragma unroll
                    for (int j = 0; j < 8; ++j)
                        acc[i][j] = fmaf(a[i][k], b[k][j], acc[i][j]);
        }
    }
    __syncthreads();

    float lsum = 0.f;
    #pragma unroll
    for (int i = 0; i < 4; ++i) {
        const long s = r0 + ty * 4 + i;
        const float rs = sRow[ty * 4 + i];
        const bool has = (s < S_LEN - 1);
        float nxt[8];
        if (has) {
            *(float4*)&nxt[0] = *(const float4*)&In[(s + 1) * N + tx * 8];
            *(float4*)&nxt[4] = *(const float4*)&In[(s + 1) * N + tx * 8 + 4];
        }
        #pragma unroll
        for (int j = 0; j < 8; ++j) {
            const float z = acc[i][j];
            const float sp = fmaxf(z, 0.f) + log1pf(__expf(-fabsf(z)));
            const float o = sp * rs;
            if (has) {
                const float d = o - nxt[j];
                lsum = fmaf(d, d, lsum);
            }
        }
    }

    const float wsum = wave_reduce(lsum);
    const int lane = tid & 63, w = tid >> 6;
    if (lane == 0) sRed[w] = wsum;
    __syncthreads();
    if (tid == 0) {
        float t = 0.f;
        #pragma unroll
        for (int w2 = 0; w2 < TPB / 64; ++w2) t += sRed[w2];
        atomicAdd(&out[0], t * inv_denom);
    }
}

extern "C" void kernel_launch(void* const* d_in, const int* in_sizes, int n_in,
                              void* d_out, int out_size, void* d_ws, size_t ws_size,
                              hipStream_t stream) {
    const float* In = (const float*)d_in[0];
    const float* WQ = (const float*)d_in[1];
    const float* WK = (const float*)d_in[2];
    float* out = (float*)d_out;
    float* M = (float*)d_ws;  // 128*128*4 = 64 KB scratch

    hipMemsetAsync(d_out, 0, 2 * sizeof(float), stream);
    mk_kernel<<<128, 128, 0, stream>>>(WQ, WK, M, out);
    const float inv = (float)(1.0 / ((double)(S_LEN - 1) * (double)N));
    main_kernel<<<S_LEN / BR, TPB, 0, stream>>>(In, M, out, inv);
}

// Round 2
// 294.900 us; speedup vs baseline: 1.1911x; 1.1911x over previous
//
#include <hip/hip_runtime.h>
#include <math.h>

#define S_LEN 262144
#define N 128
#define BR 64
#define TPB 256

typedef __attribute__((ext_vector_type(8))) short bf16x8;
typedef __attribute__((ext_vector_type(4))) float f32x4;

__device__ __forceinline__ unsigned short f2bf(float x) {
    unsigned b = __float_as_uint(x);
    b = (b + 0x7FFF + ((b >> 16) & 1)) >> 16;   // RNE truncate to bf16
    return (unsigned short)b;
}
__device__ __forceinline__ float bf2f(unsigned short u) {
    return __uint_as_float((unsigned)u << 16);
}

__device__ __forceinline__ float wave_reduce(float v) {
    #pragma unroll
    for (int off = 32; off > 0; off >>= 1) v += __shfl_down(v, off, 64);
    return v;
}

// M = W_K^T @ W_Q (128x128). Emit bf16 hi/lo in MFMA-B-fragment order:
//   frag[((kk*8 + ct)*64 + lane)*8 + j] = M[kk*32 + (lane>>4)*8 + j][ct*16 + (lane&15)]
// Also l1 = sum(sigmoid(M)) -> out[1].
__global__ void mk_kernel(const float* __restrict__ WQ, const float* __restrict__ WK,
                          unsigned short* __restrict__ fragHi,
                          unsigned short* __restrict__ fragLo,
                          float* __restrict__ out) {
    const int i = blockIdx.x;   // M row (k index of main GEMM) -- uniform => scalar loads
    const int j = threadIdx.x;  // M col
    float acc = 0.f;
    #pragma unroll 8
    for (int r = 0; r < N; ++r) acc = fmaf(WK[r * N + i], WQ[r * N + j], acc);

    const unsigned short hi = f2bf(acc);
    const unsigned short lo = f2bf(acc - bf2f(hi));
    const int kk = i >> 5, q = (i >> 3) & 3, jj = i & 7;
    const int ct = j >> 4, n15 = j & 15;
    const int idx = ((kk * 8 + ct) * 64 + (q * 16 + n15)) * 8 + jj;
    fragHi[idx] = hi;
    fragLo[idx] = lo;

    float sg = fabsf(1.0f / (1.0f + __expf(-acc)));
    float ws = wave_reduce(sg);
    __shared__ float red[2];
    const int lane = j & 63, w = j >> 6;
    if (lane == 0) red[w] = ws;
    __syncthreads();
    if (j == 0) atomicAdd(&out[1], red[0] + red[1]);
}

// z = In @ M via bf16 hi/lo MFMA (fp32-accurate); Out = softplus(z)*rowsum(In);
// loss += sum((Out[s]-In[s+1])^2) * inv_denom -> out[0].
__global__ __launch_bounds__(TPB, 3) void main_kernel(
    const float* __restrict__ In,
    const unsigned short* __restrict__ fragHi,
    const unsigned short* __restrict__ fragLo,
    float* __restrict__ out, float inv_denom) {
    __shared__ unsigned short sHi[BR][136];   // 64 rows x 128 k, pad->136 (2-way max, free)
    __shared__ unsigned short sLo[BR][136];
    __shared__ float sPart[BR][4];
    __shared__ float sRed[TPB / 64];

    const int tid = threadIdx.x;
    const int w = tid >> 6, lane = tid & 63;
    const int q = lane >> 4, n15 = lane & 15;
    const long r0 = (long)blockIdx.x * BR;

    // B fragments (all of M for this wave's 32 cols), coalesced 16B loads from L2
    bf16x8 bHi[2][4], bLo[2][4];
    #pragma unroll
    for (int c = 0; c < 2; ++c)
        #pragma unroll
        for (int kk = 0; kk < 4; ++kk) {
            const int base = ((kk * 8 + (w * 2 + c)) * 64 + lane) * 8;
            bHi[c][kk] = *(const bf16x8*)&fragHi[base];
            bLo[c][kk] = *(const bf16x8*)&fragLo[base];
        }

    // stage 64x128 fp32 tile -> bf16 hi/lo LDS (coalesced float4 global reads)
    #pragma unroll
    for (int t = 0; t < 8; ++t) {
        const int qq = tid + t * TPB;        // 0..2047
        const int r = qq >> 5;
        const int c4 = (qq & 31) << 2;
        const float4 v = *(const float4*)&In[(r0 + r) * N + c4];
        ushort4 h, l;
        h.x = f2bf(v.x); l.x = f2bf(v.x - bf2f(h.x));
        h.y = f2bf(v.y); l.y = f2bf(v.y - bf2f(h.y));
        h.z = f2bf(v.z); l.z = f2bf(v.z - bf2f(h.z));
        h.w = f2bf(v.w); l.w = f2bf(v.w - bf2f(h.w));
        *(ushort4*)&sHi[r][c4] = h;
        *(ushort4*)&sLo[r][c4] = l;
    }
    __syncthreads();

    // row-sum partials: thread t sums 32 elems (hi+lo) of row t>>2
    {
        const int r = tid >> 2, cg = (tid & 3) << 5;
        float s = 0.f;
        #pragma unroll
        for (int m = 0; m < 4; ++m) {
            bf16x8 hv = *(const bf16x8*)&sHi[r][cg + m * 8];
            bf16x8 lv = *(const bf16x8*)&sLo[r][cg + m * 8];
            #pragma unroll
            for (int e = 0; e < 8; ++e)
                s += bf2f((unsigned short)hv[e]) + bf2f((unsigned short)lv[e]);
        }
        sPart[r][tid & 3] = s;
    }

    // MFMA: acc = InHi@MHi + InHi@MLo + InLo@MHi  (fp32 accumulate)
    f32x4 acc[4][2];
    #pragma unroll
    for (int rt = 0; rt < 4; ++rt)
        #pragma unroll
        for (int c = 0; c < 2; ++c)
            acc[rt][c] = (f32x4){0.f, 0.f, 0.f, 0.f};

    #pragma unroll
    for (int rt = 0; rt < 4; ++rt) {
        #pragma unroll
        for (int kk = 0; kk < 4; ++kk) {
            const int row = rt * 16 + n15;       // A[m=lane&15][k=q*8+j]
            const int kof = kk * 32 + q * 8;
            bf16x8 aHi = *(const bf16x8*)&sHi[row][kof];
            bf16x8 aLo = *(const bf16x8*)&sLo[row][kof];
            #pragma unroll
            for (int c = 0; c < 2; ++c) {
                acc[rt][c] = __builtin_amdgcn_mfma_f32_16x16x32_bf16(aHi, bHi[c][kk], acc[rt][c], 0, 0, 0);
                acc[rt][c] = __builtin_amdgcn_mfma_f32_16x16x32_bf16(aHi, bLo[c][kk], acc[rt][c], 0, 0, 0);
                acc[rt][c] = __builtin_amdgcn_mfma_f32_16x16x32_bf16(aLo, bHi[c][kk], acc[rt][c], 0, 0, 0);
            }
        }
    }
    __syncthreads();   // sPart visible to all readers

    // epilogue: C/D row = q*4+reg, col = w*32 + c*16 + n15
    float lsum = 0.f;
    #pragma unroll
    for (int rt = 0; rt < 4; ++rt) {
        #pragma unroll
        for (int reg = 0; reg < 4; ++reg) {
            const int row = rt * 16 + q * 4 + reg;
            const float4 p = *(const float4*)&sPart[row][0];
            const float rs = p.x + p.y + p.z + p.w;
            const long s = r0 + row;
            const bool has = (s < S_LEN - 1);
            #pragma unroll
            for (int c = 0; c < 2; ++c) {
                const float z = acc[rt][c][reg];
                const float sp = fmaxf(z, 0.f) + log1pf(__expf(-fabsf(z)));
                const float o = sp * rs;
                if (has) {
                    const int col = w * 32 + c * 16 + n15;
                    const float d = o - In[(s + 1) * N + col];
                    lsum = fmaf(d, d, lsum);
                }
            }
        }
    }

    const float wsum = wave_reduce(lsum);
    if ((tid & 63) == 0) sRed[w] = wsum;
    __syncthreads();
    if (tid == 0) {
        float t = 0.f;
        #pragma unroll
        for (int w2 = 0; w2 < TPB / 64; ++w2) t += sRed[w2];
        atomicAdd(&out[0], t * inv_denom);
    }
}

extern "C" void kernel_launch(void* const* d_in, const int* in_sizes, int n_in,
                              void* d_out, int out_size, void* d_ws, size_t ws_size,
                              hipStream_t stream) {
    const float* In = (const float*)d_in[0];
    const float* WQ = (const float*)d_in[1];
    const float* WK = (const float*)d_in[2];
    float* out = (float*)d_out;
    unsigned short* fragHi = (unsigned short*)d_ws;            // 32 KB
    unsigned short* fragLo = fragHi + 128 * 128;               // 32 KB

    hipMemsetAsync(d_out, 0, 2 * sizeof(float), stream);
    mk_kernel<<<128, 128, 0, stream>>>(WQ, WK, fragHi, fragLo, out);
    const float inv = (float)(1.0 / ((double)(S_LEN - 1) * (double)N));
    main_kernel<<<S_LEN / BR, TPB, 0, stream>>>(In, fragHi, fragLo, out, inv);
}

// Round 3
// 234.148 us; speedup vs baseline: 1.5001x; 1.2595x over previous
//
#include <hip/hip_runtime.h>
#include <math.h>

#define S_LEN 262144
#define N 128
#define BR 64
#define TPB 256

typedef __attribute__((ext_vector_type(8))) short bf16x8;
typedef __attribute__((ext_vector_type(4))) float f32x4;

__device__ __forceinline__ unsigned short f2bf(float x) {
    unsigned b = __float_as_uint(x);
    b = (b + 0x7FFF + ((b >> 16) & 1)) >> 16;   // RNE to bf16
    return (unsigned short)b;
}

__device__ __forceinline__ float wave_reduce(float v) {
    #pragma unroll
    for (int off = 32; off > 0; off >>= 1) v += __shfl_down(v, off, 64);
    return v;
}

// M = W_K^T @ W_Q (128x128) in fp32; emit bf16 in MFMA-B-fragment order:
//   frag[((kk*8 + ct)*64 + lane)*8 + j] = M[kk*32 + (lane>>4)*8 + j][ct*16 + (lane&15)]
// Also l1 = sum(sigmoid(M)) -> out[1] (fp32-accurate).
__global__ void mk_kernel(const float* __restrict__ WQ, const float* __restrict__ WK,
                          unsigned short* __restrict__ fragB, float* __restrict__ out) {
    const int i = blockIdx.x;   // M row (k index of main GEMM)
    const int j = threadIdx.x;  // M col
    float acc = 0.f;
    #pragma unroll 8
    for (int r = 0; r < N; ++r) acc = fmaf(WK[r * N + i], WQ[r * N + j], acc);

    const int kk = i >> 5, q = (i >> 3) & 3, jj = i & 7;
    const int ct = j >> 4, n15 = j & 15;
    fragB[((kk * 8 + ct) * 64 + (q * 16 + n15)) * 8 + jj] = f2bf(acc);

    float sg = fabsf(1.0f / (1.0f + __expf(-acc)));
    float ws = wave_reduce(sg);
    __shared__ float red[2];
    if ((j & 63) == 0) red[j >> 6] = ws;
    __syncthreads();
    if (j == 0) atomicAdd(&out[1], red[0] + red[1]);
}

// z = In @ M via bf16 MFMA; Out = softplus(z)*rowsum_f32(In);
// loss += sum((Out[s]-In[s+1])^2) * inv_denom -> out[0].
__global__ __launch_bounds__(TPB, 4) void main_kernel(
    const float* __restrict__ In, const unsigned short* __restrict__ fragB,
    float* __restrict__ out, float inv_denom) {
    __shared__ unsigned short sA[BR][136];   // 64 x 128 bf16, pad 136 (2-way max)
    __shared__ float sPartF[BR][33];         // fp32 rowsum partials, pad 33 (2-way)
    __shared__ float sPart[BR][4];
    __shared__ float sRed[TPB / 64];

    const int tid = threadIdx.x;
    const int w = tid >> 6, lane = tid & 63;
    const int q = lane >> 4, n15 = lane & 15;
    const long r0 = (long)blockIdx.x * BR;

    // B fragments for this wave's 32 output cols (L2-hot, coalesced 16B)
    bf16x8 bF[2][4];
    #pragma unroll
    for (int c = 0; c < 2; ++c)
        #pragma unroll
        for (int kk = 0; kk < 4; ++kk)
            bF[c][kk] = *(const bf16x8*)&fragB[((kk * 8 + (w * 2 + c)) * 64 + lane) * 8];

    // stage 64x128 fp32 -> bf16 LDS; fp32 rowsum partials on the fly
    #pragma unroll
    for (int t = 0; t < 8; ++t) {
        const int qq = tid + t * TPB;        // 0..2047
        const int r = qq >> 5;
        const int c4 = (qq & 31) << 2;
        const float4 v = *(const float4*)&In[(r0 + r) * N + c4];
        ushort4 h;
        h.x = f2bf(v.x); h.y = f2bf(v.y); h.z = f2bf(v.z); h.w = f2bf(v.w);
        *(ushort4*)&sA[r][c4] = h;
        sPartF[r][qq & 31] = v.x + v.y + v.z + v.w;
    }
    __syncthreads();

    // rowsum: thread handles 8 partials of row tid>>2, slot tid&3
    {
        const int r = tid >> 2, sg = (tid & 3) << 3;
        float s = 0.f;
        #pragma unroll
        for (int e = 0; e < 8; ++e) s += sPartF[r][sg + e];
        sPart[r][tid & 3] = s;
    }

    // MFMA: 4 row-tiles x 2 col-tiles, K=128
    f32x4 acc[4][2];
    #pragma unroll
    for (int rt = 0; rt < 4; ++rt)
        #pragma unroll
        for (int c = 0; c < 2; ++c) acc[rt][c] = (f32x4){0.f, 0.f, 0.f, 0.f};

    #pragma unroll
    for (int rt = 0; rt < 4; ++rt) {
        #pragma unroll
        for (int kk = 0; kk < 4; ++kk) {
            bf16x8 a = *(const bf16x8*)&sA[rt * 16 + n15][kk * 32 + q * 8];
            #pragma unroll
            for (int c = 0; c < 2; ++c)
                acc[rt][c] = __builtin_amdgcn_mfma_f32_16x16x32_bf16(a, bF[c][kk], acc[rt][c], 0, 0, 0);
        }
    }
    __syncthreads();   // sPart visible

    // epilogue: C/D row = q*4+reg (in 16-blk), col = w*32 + c*16 + n15
    float lsum = 0.f;
    #pragma unroll
    for (int rt = 0; rt < 4; ++rt) {
        #pragma unroll
        for (int reg = 0; reg < 4; ++reg) {
            const int row = rt * 16 + q * 4 + reg;
            const float4 p = *(const float4*)&sPart[row][0];
            const float rs = p.x + p.y + p.z + p.w;
            const long s = r0 + row;
            const bool has = (s < S_LEN - 1);
            #pragma unroll
            for (int c = 0; c < 2; ++c) {
                const float z = acc[rt][c][reg];
                const float sp = fmaxf(z, 0.f) + __logf(1.0f + __expf(-fabsf(z)));
                const float o = sp * rs;
                if (has) {
                    const int col = w * 32 + c * 16 + n15;
                    const float d = o - In[(s + 1) * N + col];
                    lsum = fmaf(d, d, lsum);
                }
            }
        }
    }

    const float wsum = wave_reduce(lsum);
    if ((tid & 63) == 0) sRed[w] = wsum;
    __syncthreads();
    if (tid == 0) {
        float t = 0.f;
        #pragma unroll
        for (int w2 = 0; w2 < TPB / 64; ++w2) t += sRed[w2];
        atomicAdd(&out[0], t * inv_denom);
    }
}

extern "C" void kernel_launch(void* const* d_in, const int* in_sizes, int n_in,
                              void* d_out, int out_size, void* d_ws, size_t ws_size,
                              hipStream_t stream) {
    const float* In = (const float*)d_in[0];
    const float* WQ = (const float*)d_in[1];
    const float* WK = (const float*)d_in[2];
    float* out = (float*)d_out;
    unsigned short* fragB = (unsigned short*)d_ws;   // 32 KB

    hipMemsetAsync(d_out, 0, 2 * sizeof(float), stream);
    mk_kernel<<<128, 128, 0, stream>>>(WQ, WK, fragB, out);
    const float inv = (float)(1.0 / ((double)(S_LEN - 1) * (double)N));
    main_kernel<<<S_LEN / BR, TPB, 0, stream>>>(In, fragB, out, inv);
}